// Round 4
// baseline (827.182 us; speedup 1.0000x reference)
//
#include <hip/hip_runtime.h>
#include <hip/hip_bf16.h>

// Qwen3-Next GatedDeltaNet prefill, B=2, S=2048, HK=16, HV=32, DK=DV=128, K=4.
// Round 8: 2-token algebraic batching (mini-WY). Round-7 counters: 747 cy/tok
// at 53% VALUBusy -> still serial-latency-bound (dot chain -> red8 -> delta ->
// S update per token, 1 wave/SIMD so no TLP). Reassociate the recurrence so
// BOTH tokens' dots (k0S,k1S,k1k0,q0S,q1S,q0k0,q1k0,q1k1) run in parallel
// against S_prev: one reduction latency per PAIR; 8 red8 chains overlap.
//   d0 = b0(v0 - eg0*(k0.S));  p1 = eg0eg1*(k1.S) + eg1*(k1.k0)*d0
//   d1 = b1(v1 - p1);          S  = eg0eg1*S + (eg1 d0)*k0 + d1*k1
//   o0 = eg0(q0.S) + (q0.k0)d0; o1 = eg0eg1(q1.S)+eg1(q1.k0)d0+(q1.k1)d1
// LDS ring / DMA / vmcnt(35) (16 stores + 19 loads per 16-tok chunk) unchanged.

#define B_    2
#define S_    2048
#define HK_   16
#define HV_   32
#define DK_   128
#define QKV_  8192
#define EPS_  1e-6f
#define SCALE_ 0.08838834764831845f   // 128^-0.5
#define CH_   16
#define NCH_  (S_ / CH_)

#define AS_GLOBAL __attribute__((address_space(1)))
#define AS_LDS    __attribute__((address_space(3)))

__device__ __forceinline__ void gload16(const float* src, float* dst) {
    __builtin_amdgcn_global_load_lds((const AS_GLOBAL void*)src,
                                     (AS_LDS void*)dst, 16, 0, 0);
}
__device__ __forceinline__ void gload4(const float* src, float* dst) {
    __builtin_amdgcn_global_load_lds((const AS_GLOBAL void*)src,
                                     (AS_LDS void*)dst, 4, 0, 0);
}

// 8-lane sum over lanes sharing (lane>>3): all stages VALU-latency DPP.
__device__ __forceinline__ float red8(float x) {
    int t;
    t = __builtin_amdgcn_update_dpp(0, __float_as_int(x), 0xB1, 0xF, 0xF, true);
    x += __int_as_float(t);                               // + lane^1
    t = __builtin_amdgcn_update_dpp(0, __float_as_int(x), 0x4E, 0xF, 0xF, true);
    x += __int_as_float(t);                               // + lane^2
    t = __builtin_amdgcn_update_dpp(0, __float_as_int(x), 0x141, 0xF, 0xF, true);
    x += __int_as_float(t);                               // + lane^4 (via ^7)
    return x;
}

// ---------------------------------------------------------------------------
// Preprocess: y = silu(causal_conv(x)); q/k l2-normalized per 128-ch head,
// q pre-scaled by DK^-0.5. Y layout = x layout: [B*S, 8192].
// grid (4 segs, B*S/4), block 256, 8 ch/thread, 4 tokens/block (rolling hist).
// ---------------------------------------------------------------------------
__global__ __launch_bounds__(256)
void preproc_kernel(const float* __restrict__ x, const float* __restrict__ w,
                    float* __restrict__ Y)
{
    const int seg = blockIdx.x;            // 0:q 1:k 2,3:v
    const int bt0 = blockIdx.y * 4;        // first global row of this block
    const int t0  = bt0 & (S_ - 1);        // token within sequence
    const int tid = threadIdx.x;
    const int c0  = seg * 2048 + tid * 8;

    float4 w4[8];
#pragma unroll
    for (int i = 0; i < 8; ++i)
        w4[i] = *reinterpret_cast<const float4*>(&w[(c0 + i) * 4]);

    float h0[8], h1[8], h2[8], cur[8], y[8];

#pragma unroll
    for (int i = 0; i < 8; ++i) { h0[i] = 0.f; h1[i] = 0.f; h2[i] = 0.f; }
    if (t0 >= 3) {   // t0 is a multiple of 4, so either 0 (all zero) or >=4
        const float* r0 = &x[(size_t)(bt0 - 3) * QKV_ + c0];
        const float* r1 = &x[(size_t)(bt0 - 2) * QKV_ + c0];
        const float* r2 = &x[(size_t)(bt0 - 1) * QKV_ + c0];
#pragma unroll
        for (int i4 = 0; i4 < 2; ++i4) {
            const float4 a = *reinterpret_cast<const float4*>(r0 + i4 * 4);
            const float4 b = *reinterpret_cast<const float4*>(r1 + i4 * 4);
            const float4 c = *reinterpret_cast<const float4*>(r2 + i4 * 4);
            h0[4*i4+0]=a.x; h0[4*i4+1]=a.y; h0[4*i4+2]=a.z; h0[4*i4+3]=a.w;
            h1[4*i4+0]=b.x; h1[4*i4+1]=b.y; h1[4*i4+2]=b.z; h1[4*i4+3]=b.w;
            h2[4*i4+0]=c.x; h2[4*i4+1]=c.y; h2[4*i4+2]=c.z; h2[4*i4+3]=c.w;
        }
    }

#pragma unroll
    for (int tt = 0; tt < 4; ++tt) {
        const float* rc = &x[(size_t)(bt0 + tt) * QKV_ + c0];
#pragma unroll
        for (int i4 = 0; i4 < 2; ++i4) {
            const float4 a = *reinterpret_cast<const float4*>(rc + i4 * 4);
            cur[4*i4+0]=a.x; cur[4*i4+1]=a.y; cur[4*i4+2]=a.z; cur[4*i4+3]=a.w;
        }
#pragma unroll
        for (int i = 0; i < 8; ++i) {
            float v = h0[i]*w4[i].x + h1[i]*w4[i].y + h2[i]*w4[i].z + cur[i]*w4[i].w;
            y[i] = v / (1.f + expf(-v));                 // silu
        }
        if (seg < 2) {                                    // l2norm over 128 ch = 16 lanes
            float s = 0.f;
#pragma unroll
            for (int i = 0; i < 8; ++i) s += y[i] * y[i];
#pragma unroll
            for (int off = 8; off >= 1; off >>= 1)
                s += __shfl_xor(s, off, 64);
            float rn = rsqrtf(s + EPS_);
            if (seg == 0) rn *= SCALE_;
#pragma unroll
            for (int i = 0; i < 8; ++i) y[i] *= rn;
        }
        float4* dst = reinterpret_cast<float4*>(&Y[(size_t)(bt0 + tt) * QKV_ + c0]);
        dst[0] = make_float4(y[0], y[1], y[2], y[3]);
        dst[1] = make_float4(y[4], y[5], y[6], y[7]);
#pragma unroll
        for (int i = 0; i < 8; ++i) { h0[i] = h1[i]; h1[i] = h2[i]; h2[i] = cur[i]; }
    }
}

// ---------------------------------------------------------------------------
// Gating: GB[i] = (exp(-exp(alog)*softplus(a+dt_bias)), sigmoid(b)). [B*S,HV]
// ---------------------------------------------------------------------------
__global__ __launch_bounds__(256)
void gating_kernel(const float* __restrict__ bin, const float* __restrict__ ain,
                   const float* __restrict__ dtb, const float* __restrict__ alg,
                   float2* __restrict__ GB)
{
    const int i = blockIdx.x * 256 + threadIdx.x;
    if (i >= B_ * S_ * HV_) return;
    const int h = i & (HV_ - 1);
    const float av = ain[i] + dtb[h];
    const float sp = (av > 20.f) ? av : log1pf(expf(av));
    GB[i] = make_float2(expf(-expf(alg[h]) * sp), 1.f / (1.f + expf(-bin[i])));
}

// ---------------------------------------------------------------------------
// Recurrence helpers
// ---------------------------------------------------------------------------
__device__ __forceinline__ void lds_load_kqv(const float* __restrict__ Kt,
                                             const float* __restrict__ Qt,
                                             const float* __restrict__ Vt,
                                             int kh, int vloc, int sw,
                                             float (&kf)[16], float (&qf)[16],
                                             float& vv)
{
    // read granules in order (r ^ sw): per-instruction lane granules are
    // distinct mod 8 -> conflict-free ds_read_b128. Register indices STATIC;
    // the per-thread granule permutation is shared by kf/qf/S so all dot
    // products and elementwise updates stay consistent.
#pragma unroll
    for (int r = 0; r < 4; ++r) {
        const int idx = r ^ sw;                           // LDS address only
        const float4 kq = *reinterpret_cast<const float4*>(Kt + kh * 16 + idx * 4);
        const float4 qq = *reinterpret_cast<const float4*>(Qt + kh * 16 + idx * 4);
        kf[4*r+0]=kq.x; kf[4*r+1]=kq.y; kf[4*r+2]=kq.z; kf[4*r+3]=kq.w;
        qf[4*r+0]=qq.x; qf[4*r+1]=qq.y; qf[4*r+2]=qq.z; qf[4*r+3]=qq.w;
    }
    vv = Vt[vloc];
}

// One 2-token step. All 8 dots are against S_prev (independent, parallel);
// one reduction latency per pair; scalar resolve; fused 3-FMA S update.
__device__ __forceinline__ void step_pair(float (&S)[16],
    const float (&k0)[16], const float (&q0)[16], float v0,
    const float (&k1)[16], const float (&q1)[16], float v1,
    float4 g,                       // (eg0, b0, eg1, b1)
    int kh, float* __restrict__ o0p, float* __restrict__ o1p)
{
    float a0 = 0.f, a1 = 0.f, cc = 0.f, u0 = 0.f,
          u1 = 0.f, w00 = 0.f, w10 = 0.f, w11 = 0.f;
#pragma unroll
    for (int j = 0; j < 16; ++j) {
        a0  += k0[j] * S[j];
        a1  += k1[j] * S[j];
        cc  += k1[j] * k0[j];
        u0  += q0[j] * S[j];
        u1  += q1[j] * S[j];
        w00 += q0[j] * k0[j];
        w10 += q1[j] * k0[j];
        w11 += q1[j] * k1[j];
    }
    a0 = red8(a0);  a1 = red8(a1);  cc = red8(cc);  u0 = red8(u0);
    u1 = red8(u1);  w00 = red8(w00); w10 = red8(w10); w11 = red8(w11);

    const float eg0 = g.x, b0 = g.y, eg1 = g.z, b1 = g.w;
    const float d0   = b0 * (v0 - eg0 * a0);
    const float eg01 = eg0 * eg1;
    const float p1   = fmaf(eg1 * cc, d0, eg01 * a1);
    const float d1   = b1 * (v1 - p1);
    const float o0   = fmaf(w00, d0, eg0 * u0);
    const float o1   = fmaf(w11, d1, fmaf(eg1 * w10, d0, eg01 * u1));
    const float bb   = eg1 * d0;
#pragma unroll
    for (int j = 0; j < 16; ++j)
        S[j] = fmaf(eg01, S[j], fmaf(bb, k0[j], d1 * k1[j]));

    if (kh == 0) { *o0p = o0; *o1p = o1; }
}

// ---------------------------------------------------------------------------
// Recurrence: grid (HV, B, 16 v-slices) = 1024 single-wave blocks, 64 threads.
// thread = (vcol = vs*8 + lane>>3, kh = lane&7); owns S[kh*16 .. +15][vcol].
// 16-token chunks staged to LDS (double-buffered) via global_load_lds; the
// chunk c+2 DMA is issued after computing chunk c and kept in flight with
// s_waitcnt vmcnt(35) = 19 loads + 16 o-stores (in-order vmcnt retirement
// guarantees chunk c+1's older loads have landed). Compute runs on PAIRS
// (8 per chunk) with a pair-level A/B register double buffer.
// ---------------------------------------------------------------------------
__global__ __launch_bounds__(64, 1)
void recur_kernel(const float* __restrict__ Y, const float2* __restrict__ GB,
                  float* __restrict__ out)
{
    const int h    = blockIdx.x;
    const int b    = blockIdx.y;
    const int vs   = blockIdx.z;
    const int hk   = h >> 1;
    const int lane = threadIdx.x;
    const int kh   = lane & 7;
    const int vloc = lane >> 3;
    const int sw   = kh >> 1;

    const int qoff0 = hk * DK_;
    const int koff0 = 2048 + hk * DK_;
    const int voff0 = 4096 + h * DK_ + vs * 8;

    // 34304 B static LDS -> 4 blocks/CU co-resident (4*34304 <= 160 KiB)
    __shared__ __align__(16) float Ksm[2][CH_][128];
    __shared__ __align__(16) float Qsm[2][CH_][128];
    __shared__ __align__(16) float Vsm[2][CH_ * 8];
    __shared__ __align__(16) float Gsm[2][64];

    const float* rowBase = Y + (size_t)(b * S_) * QKV_;
    const float* gflat   = (const float*)(GB + (size_t)(b * S_) * HV_ + h);
    float* obase = out + ((size_t)(b * S_) * HV_ + h) * (size_t)DK_ + vs * 8 + vloc;

    // DMA lane roles
    const int tk = lane >> 5;      // K/Q: which of 2 tokens per 1 KiB instr
    const int gr = lane & 31;      // 16-B granule within a 512-B row

    auto issue_chunk = [&](int t0, int bsel) {
#pragma unroll
        for (int i = 0; i < 8; ++i)     // K: 8 x 16B, 2 tokens each
            gload16(rowBase + (size_t)(t0 + 2 * i + tk) * QKV_ + koff0 + gr * 4,
                    &Ksm[bsel][2 * i][0]);
#pragma unroll
        for (int i = 0; i < 8; ++i)     // Q: 8 x 16B
            gload16(rowBase + (size_t)(t0 + 2 * i + tk) * QKV_ + qoff0 + gr * 4,
                    &Qsm[bsel][2 * i][0]);
#pragma unroll
        for (int i = 0; i < 2; ++i)     // V: 2 x 4B, 8 tokens each
            gload4(rowBase + (size_t)(t0 + i * 8 + (lane >> 3)) * QKV_
                           + voff0 + (lane & 7),
                   &Vsm[bsel][i * 64]);
        // G: 1 x 4B; lanes >=32 duplicate into padding
        gload4(gflat + (size_t)(t0 + ((lane >> 1) & 15)) * (HV_ * 2) + (lane & 1),
               &Gsm[bsel][0]);
    };

    float S[16];
#pragma unroll
    for (int j = 0; j < 16; ++j) S[j] = 0.f;

    issue_chunk(0, 0);
    issue_chunk(CH_, 1);
    asm volatile("s_waitcnt vmcnt(19)" ::: "memory");   // chunk 0 landed

    // pair-level A/B register double buffer
    float k0A[16], q0A[16], k1A[16], q1A[16], v0A, v1A;
    float k0B[16], q0B[16], k1B[16], q1B[16], v0B, v1B;
    float4 gA, gB4;

    for (int c = 0; c < NCH_; ++c) {
        const int bsel = c & 1;
        const int t0   = c * CH_;
        const float (*Kc)[128] = Ksm[bsel];
        const float (*Qc)[128] = Qsm[bsel];
        const float* Vc = Vsm[bsel];
        const float* Gc = Gsm[bsel];

        // load pairs 0 and 1
        lds_load_kqv(Kc[0], Qc[0], Vc + 0,  kh, vloc, sw, k0A, q0A, v0A);
        lds_load_kqv(Kc[1], Qc[1], Vc + 8,  kh, vloc, sw, k1A, q1A, v1A);
        gA = *reinterpret_cast<const float4*>(Gc + 0);
        lds_load_kqv(Kc[2], Qc[2], Vc + 16, kh, vloc, sw, k0B, q0B, v0B);
        lds_load_kqv(Kc[3], Qc[3], Vc + 24, kh, vloc, sw, k1B, q1B, v1B);
        gB4 = *reinterpret_cast<const float4*>(Gc + 4);

#pragma unroll
        for (int pp = 0; pp < CH_ / 2; pp += 2) {      // pairs pp (A), pp+1 (B)
            step_pair(S, k0A, q0A, v0A, k1A, q1A, v1A, gA, kh,
                      obase + (size_t)(t0 + 2 * pp)     * (HV_ * DK_),
                      obase + (size_t)(t0 + 2 * pp + 1) * (HV_ * DK_));
            if (pp + 2 < CH_ / 2) {                    // refill A with pair pp+2
                const int ta = 2 * (pp + 2);
                lds_load_kqv(Kc[ta],     Qc[ta],     Vc + ta * 8,
                             kh, vloc, sw, k0A, q0A, v0A);
                lds_load_kqv(Kc[ta + 1], Qc[ta + 1], Vc + (ta + 1) * 8,
                             kh, vloc, sw, k1A, q1A, v1A);
                gA = *reinterpret_cast<const float4*>(Gc + 2 * ta);
            }
            __builtin_amdgcn_sched_barrier(0);   // pin refill-A ahead of step-B
            step_pair(S, k0B, q0B, v0B, k1B, q1B, v1B, gB4, kh,
                      obase + (size_t)(t0 + 2 * pp + 2) * (HV_ * DK_),
                      obase + (size_t)(t0 + 2 * pp + 3) * (HV_ * DK_));
            if (pp + 3 < CH_ / 2) {                    // refill B with pair pp+3
                const int tb = 2 * (pp + 3);
                lds_load_kqv(Kc[tb],     Qc[tb],     Vc + tb * 8,
                             kh, vloc, sw, k0B, q0B, v0B);
                lds_load_kqv(Kc[tb + 1], Qc[tb + 1], Vc + (tb + 1) * 8,
                             kh, vloc, sw, k1B, q1B, v1B);
                gB4 = *reinterpret_cast<const float4*>(Gc + 2 * tb);
            }
        }

        // prefetch chunk c+2 into the buffer we just finished reading
        const int tn = (c + 2 < NCH_) ? (c + 2) * CH_ : (NCH_ - 1) * CH_;
        issue_chunk(tn, bsel);
        // keep the newest 35 vmem ops (19 DMA + 16 o-stores) in flight; all
        // older ops -- incl. chunk c+1's DMA -- are retired in order.
        asm volatile("s_waitcnt vmcnt(35)" ::: "memory");
    }
}

// ---------------------------------------------------------------------------
// Fallback (round-2 monolithic kernel) if workspace is too small.
// ---------------------------------------------------------------------------
__global__ __launch_bounds__(128)
void gdn_prefill_fallback(const float* __restrict__ xqkv, const float* __restrict__ bin,
                          const float* __restrict__ ain, const float* __restrict__ wconv,
                          const float* __restrict__ dtb, const float* __restrict__ alg,
                          float* __restrict__ out)
{
    const int h = blockIdx.x, b = blockIdx.y;
    const int hk = h >> 1;
    const int tid = threadIdx.x, lane = tid & 63, wid = tid >> 6;
    __shared__ __align__(16) float ks[DK_];
    __shared__ __align__(16) float qs[DK_];
    __shared__ float redq[2], redk[2];
    const int qc = hk * DK_ + tid, kc = HK_ * DK_ + hk * DK_ + tid,
              vc = 2 * HK_ * DK_ + h * DK_ + tid;
    float wq[4], wk[4], wv[4];
#pragma unroll
    for (int j = 0; j < 4; ++j) {
        wq[j] = wconv[qc*4+j]; wk[j] = wconv[kc*4+j]; wv[j] = wconv[vc*4+j];
    }
    const float nea = -expf(alg[h]), dbi = dtb[h];
    float hq0=0,hq1=0,hq2=0,hk0=0,hk1=0,hk2=0,hv0=0,hv1=0,hv2=0;
    float Sr[DK_];
#pragma unroll
    for (int k = 0; k < DK_; ++k) Sr[k] = 0.f;
    const size_t row0 = (size_t)b * S_;
    for (int t = 0; t < S_; ++t) {
        const size_t row = row0 + t, xb = row * QKV_;
        const float xq = xqkv[xb+qc], xk = xqkv[xb+kc], xv = xqkv[xb+vc];
        float yq = hq0*wq[0]+hq1*wq[1]+hq2*wq[2]+xq*wq[3];
        float yk = hk0*wk[0]+hk1*wk[1]+hk2*wk[2]+xk*wk[3];
        float yv = hv0*wv[0]+hv1*wv[1]+hv2*wv[2]+xv*wv[3];
        hq0=hq1;hq1=hq2;hq2=xq; hk0=hk1;hk1=hk2;hk2=xk; hv0=hv1;hv1=hv2;hv2=xv;
        yq = yq/(1.f+expf(-yq)); yk = yk/(1.f+expf(-yk)); yv = yv/(1.f+expf(-yv));
        float sq = yq*yq, sk = yk*yk;
#pragma unroll
        for (int off = 32; off >= 1; off >>= 1) {
            sq += __shfl_xor(sq, off, 64); sk += __shfl_xor(sk, off, 64);
        }
        if (lane == 0) { redq[wid] = sq; redk[wid] = sk; }
        __syncthreads();
        const float qn = yq * rsqrtf(redq[0]+redq[1]+EPS_) * SCALE_;
        const float kn = yk * rsqrtf(redk[0]+redk[1]+EPS_);
        ks[tid] = kn; qs[tid] = qn;
        const size_t rab = row * HV_ + h;
        const float av = ain[rab] + dbi;
        const float sp = (av > 20.f) ? av : log1pf(expf(av));
        const float eg = expf(nea * sp);
        const float beta = 1.f/(1.f+expf(-bin[rab]));
        __syncthreads();
        float pred = 0.f;
#pragma unroll
        for (int k4 = 0; k4 < DK_/4; ++k4) {
            const float4 kv = *reinterpret_cast<const float4*>(&ks[k4*4]);
            float s;
            s = Sr[4*k4+0]*eg; Sr[4*k4+0]=s; pred += kv.x*s;
            s = Sr[4*k4+1]*eg; Sr[4*k4+1]=s; pred += kv.y*s;
            s = Sr[4*k4+2]*eg; Sr[4*k4+2]=s; pred += kv.z*s;
            s = Sr[4*k4+3]*eg; Sr[4*k4+3]=s; pred += kv.w*s;
        }
        const float delta = beta * (yv - pred);
        float o = 0.f;
#pragma unroll
        for (int k4 = 0; k4 < DK_/4; ++k4) {
            const float4 kv = *reinterpret_cast<const float4*>(&ks[k4*4]);
            const float4 qv = *reinterpret_cast<const float4*>(&qs[k4*4]);
            float s;
            s = Sr[4*k4+0]+kv.x*delta; Sr[4*k4+0]=s; o += qv.x*s;
            s = Sr[4*k4+1]+kv.y*delta; Sr[4*k4+1]=s; o += qv.y*s;
            s = Sr[4*k4+2]+kv.z*delta; Sr[4*k4+2]=s; o += qv.z*s;
            s = Sr[4*k4+3]+kv.w*delta; Sr[4*k4+3]=s; o += qv.w*s;
        }
        out[rab * DK_ + tid] = o;
    }
}

extern "C" void kernel_launch(void* const* d_in, const int* in_sizes, int n_in,
                              void* d_out, int out_size, void* d_ws, size_t ws_size,
                              hipStream_t stream) {
    const float* xqkv  = (const float*)d_in[0];
    const float* bin   = (const float*)d_in[1];
    const float* ain   = (const float*)d_in[2];
    const float* wconv = (const float*)d_in[3];
    const float* dtb   = (const float*)d_in[4];
    const float* alg   = (const float*)d_in[5];
    float* out = (float*)d_out;

    const size_t Y_BYTES = (size_t)B_ * S_ * QKV_ * 4;         // 134 MB
    const size_t G_BYTES = (size_t)B_ * S_ * HV_ * 8;          // 1 MB (float2)
    const size_t NEEDED  = Y_BYTES + G_BYTES;

    if (ws_size >= NEEDED) {
        float*  Y  = (float*)d_ws;
        float2* GB = (float2*)((char*)d_ws + Y_BYTES);

        preproc_kernel<<<dim3(4, B_ * S_ / 4), 256, 0, stream>>>(xqkv, wconv, Y);
        gating_kernel<<<dim3((B_ * S_ * HV_ + 255) / 256), 256, 0, stream>>>(
            bin, ain, dtb, alg, GB);
        recur_kernel<<<dim3(HV_, B_, 16), 64, 0, stream>>>(Y, GB, out);
    } else {
        gdn_prefill_fallback<<<dim3(HV_, B_), 128, 0, stream>>>(
            xqkv, bin, ain, wconv, dtb, alg, out);
    }
}